// Round 7
// baseline (214.155 us; speedup 1.0000x reference)
//
#include <hip/hip_runtime.h>
#include <math.h>

#define NPROB (64 * 2048)

__host__ __device__ constexpr int TRI(int i, int j) { return i * 13 - i * (i - 1) / 2 + (j - i); }
__host__ __device__ constexpr int OI6(int i, int j) { return i * 6 - i * (i - 1) / 2 + (j - i); }
__host__ __device__ constexpr int QI(int i, int j)  { return i * 7 - i * (i - 1) / 2 + (j - i); }

// Sparse pattern of P's columns. Entry value = s * T[a][b], or s*1.0 if a==3.
// P rows (13): rot_rows(i) -> rows 3i..3i+2, ones row 9, translation rows 10..12.
struct PE { int r, a, b, s; };
__device__ constexpr int PLEN[7] = {6, 6, 6, 3, 3, 3, 13};
__device__ constexpr PE PAT[7][13] = {
    {{1,0,2,1},{2,0,1,-1},{4,1,2,1},{5,1,1,-1},{7,2,2,1},{8,2,1,-1}},
    {{0,0,2,-1},{2,0,0,1},{3,1,2,-1},{5,1,0,1},{6,2,2,-1},{8,2,0,1}},
    {{0,0,1,1},{1,0,0,-1},{3,1,1,1},{4,1,0,-1},{6,2,1,1},{7,2,0,-1}},
    {{10,0,0,1},{11,1,0,1},{12,2,0,1}},
    {{10,0,1,1},{11,1,1,1},{12,2,1,1}},
    {{10,0,2,1},{11,1,2,1},{12,2,2,1}},
    {{0,0,0,1},{1,0,1,1},{2,0,2,1},{3,1,0,1},{4,1,1,1},{5,1,2,1},
     {6,2,0,1},{7,2,1,1},{8,2,2,1},{9,3,0,1},{10,0,3,1},{11,1,3,1},{12,2,3,1}},
};

// Fast fp64 reciprocal: v_rcp_f64 seed + 2 Newton steps -> ~1 ulp.
__device__ __forceinline__ double fast_rcp(double w) {
    double r = __builtin_amdgcn_rcp(w);
    double e = fma(-w, r, 1.0);
    r = fma(r, e, r);
    e = fma(-w, r, 1.0);
    r = fma(r, e, r);
    return r;
}

// Fast fp32 reciprocal: v_rcp_f32 + 1 Newton step.
__device__ __forceinline__ float fast_rcpf(float w) {
    float r = __builtin_amdgcn_rcpf(w);
    r = r * fmaf(-w, r, 2.0f);
    return r;
}

// fp32 Q = P^T M P build.
__device__ __forceinline__ void build_q(const float mreg[91], const float tf[3][4],
                                        float qf[28]) {
    #pragma unroll
    for (int l = 0; l < 7; ++l) {
        float y[13];
        #pragma unroll
        for (int r = 0; r < 13; ++r) y[r] = 0.0f;
        #pragma unroll
        for (int e = 0; e < 13; ++e) {
            if (e < PLEN[l]) {
                const PE pe = PAT[l][e];
                const float tt = (pe.a == 3) ? 1.0f : tf[pe.a][pe.b];
                const float cf = (pe.s > 0) ? tt : -tt;
                const int c = pe.r;
                #pragma unroll
                for (int r = 0; r < 13; ++r)
                    y[r] += cf * mreg[(r <= c) ? TRI(r, c) : TRI(c, r)];
            }
        }
        #pragma unroll
        for (int k = 0; k <= l; ++k) {
            float acc = 0.0f;
            #pragma unroll
            for (int e = 0; e < 13; ++e) {
                if (e < PLEN[k]) {
                    const PE pe = PAT[k][e];
                    const float tt = (pe.a == 3) ? 1.0f : tf[pe.a][pe.b];
                    const float cf = (pe.s > 0) ? tt : -tt;
                    acc += cf * y[pe.r];
                }
            }
            qf[QI(k, l)] = acc;
        }
    }
}

// ============================ KERNEL 1: pure fp32 ============================
// 4 fp32 GN iterations (numerics proven: absmax identical to fp64 trajectory,
// rounds 5/6) + the 5th Q build. NO fp64 anywhere -> its own register
// allocation stays in the ~124 regime every fast build this session had.
// Round-5/6 lesson: fp32 loop + fp64 tail in ONE kernel always regallocs to
// 220+ VGPRs and ~100 us; the kernel boundary is the only real containment.
// Hands off to kernel 2 via the output buffer (stream-ordered):
//   T slot  [prob*16 + 0..11]            <- tF rows 0..2
//   Om slot [NPROB*16 + prob*36 + 0..27] <- qf
__global__ __launch_bounds__(256, 1) void gn_f32_kernel(const float* __restrict__ Mg,
                                                        const float* __restrict__ Tg,
                                                        float* __restrict__ outg) {
    const int tid  = threadIdx.x;
    const int lane = tid & 63;
    const int wv   = tid >> 6;
    const long long prob = (long long)blockIdx.x * 256 + tid;

    // Stage 64 problems (64*169 floats = 43.3 KB) at a time; each wave then
    // pulls its own symmetric triangle (91 fp32) into registers.
    __shared__ __align__(16) float buf[64 * 169];
    float mreg[91];

    #pragma unroll 1
    for (int w = 0; w < 4; ++w) {
        const long long c0 = (long long)blockIdx.x * 256 + (long long)w * 64;
        const float4* src = (const float4*)(Mg + c0 * 169);
        float4* dst = (float4*)buf;
        #pragma unroll 1
        for (int i = tid; i < (64 * 169) / 4; i += 256) dst[i] = src[i];
        __syncthreads();
        if (wv == w) {
            #pragma unroll
            for (int i = 0; i < 13; ++i)
                #pragma unroll
                for (int j = i; j < 13; ++j)
                    mreg[TRI(i, j)] = buf[lane * 169 + i * 13 + j];
        }
        __syncthreads();
    }

    // fp32 master pose (bottom row of input is (0,0,0,1) and stays so).
    float tF[3][4];
    {
        const float* tp = Tg + prob * 16;
        #pragma unroll
        for (int i = 0; i < 3; ++i)
            #pragma unroll
            for (int j = 0; j < 4; ++j)
                tF[i][j] = tp[i * 4 + j];
    }

    float qf[28];

    #pragma unroll 1
    for (int it = 0; it < 4; ++it) {
        build_q(mreg, tF, qf);

        // regularization
        const float trQ  = qf[QI(3, 3)] + qf[QI(4, 4)] + qf[QI(5, 5)];
        const float regT = 1e-8f * fmaxf(trQ, 1.0f);
        qf[QI(0, 0)] += 10.0f;
        qf[QI(1, 1)] += 10.0f;
        qf[QI(2, 2)] += 10.0f;
        qf[QI(3, 3)] += regT;
        qf[QI(4, 4)] += regT;
        qf[QI(5, 5)] += regT;

        // reg2 = 1e-5 * (1 + max(Omega))
        float mx = qf[QI(0, 0)];
        #pragma unroll
        for (int k = 0; k < 6; ++k)
            #pragma unroll
            for (int l = k; l < 6; ++l)
                mx = fmaxf(mx, qf[QI(k, l)]);
        const float reg2 = 1e-5f * (1.0f + mx);
        #pragma unroll
        for (int k = 0; k < 6; ++k) qf[QI(k, k)] += reg2;

        // in-place symmetric GE on qf, col 6 as RHS
        #pragma unroll
        for (int k = 0; k < 6; ++k) {
            const float inv = fast_rcpf(qf[QI(k, k)]);
            qf[QI(k, k)] = inv;
            #pragma unroll
            for (int i = k + 1; i < 6; ++i) {
                const float f = qf[QI(k, i)] * inv;
                #pragma unroll
                for (int j = i; j < 7; ++j) qf[QI(i, j)] -= f * qf[QI(k, j)];
            }
        }
        float x[6];
        #pragma unroll
        for (int i = 5; i >= 0; --i) {
            float s = qf[QI(i, 6)];
            #pragma unroll
            for (int j = i + 1; j < 6; ++j) s -= qf[QI(i, j)] * x[j];
            x[i] = s * qf[QI(i, i)];
        }
        const float wx = -x[0], wy = -x[1], wz = -x[2];
        const float ux = -x[3], uy = -x[4], uz = -x[5];

        // fp32 closed-form expm of se(3)
        const float tsq = wx * wx + wy * wy + wz * wz;
        float A, Bc, Cc;
        if (tsq < 0.25f) {
            A  = 1.0f + tsq * (-1.0f/6 + tsq * (1.0f/120 + tsq * (-1.0f/5040 + tsq * (1.0f/362880.0f))));
            Bc = 0.5f + tsq * (-1.0f/24 + tsq * (1.0f/720 + tsq * (-1.0f/40320 + tsq * (1.0f/3628800.0f))));
            Cc = 1.0f/6 + tsq * (-1.0f/120 + tsq * (1.0f/5040 + tsq * (-1.0f/362880 + tsq * (1.0f/39916800.0f))));
        } else {
            const float th = sqrtf(tsq);
            const float s = sinf(th), c = cosf(th);
            const float rth = fast_rcpf(th), rtsq = fast_rcpf(tsq);
            A  = s * rth;
            Bc = (1.0f - c) * rtsq;
            Cc = (th - s) * rtsq * rth;
        }
        const float K2xx = wx * wx - tsq, K2yy = wy * wy - tsq, K2zz = wz * wz - tsq;
        const float K2xy = wx * wy, K2xz = wx * wz, K2yz = wy * wz;
        float R[3][3];
        R[0][0] = 1.0f + Bc * K2xx;     R[0][1] = -A * wz + Bc * K2xy;  R[0][2] =  A * wy + Bc * K2xz;
        R[1][0] =  A * wz + Bc * K2xy;  R[1][1] = 1.0f + Bc * K2yy;     R[1][2] = -A * wx + Bc * K2yz;
        R[2][0] = -A * wy + Bc * K2xz;  R[2][1] =  A * wx + Bc * K2yz;  R[2][2] = 1.0f + Bc * K2zz;
        const float V00 = 1.0f + Cc * K2xx,     V01 = -Bc * wz + Cc * K2xy, V02 =  Bc * wy + Cc * K2xz;
        const float V10 =  Bc * wz + Cc * K2xy, V11 = 1.0f + Cc * K2yy,     V12 = -Bc * wx + Cc * K2yz;
        const float V20 = -Bc * wy + Cc * K2xz, V21 =  Bc * wx + Cc * K2yz, V22 = 1.0f + Cc * K2zz;
        const float ex = V00 * ux + V01 * uy + V02 * uz;
        const float ey = V10 * ux + V11 * uy + V12 * uz;
        const float ez = V20 * ux + V21 * uy + V22 * uz;

        // T = T @ E (fp32)
        #pragma unroll
        for (int i = 0; i < 3; ++i) {
            const float a0_ = tF[i][0], a1_ = tF[i][1], a2_ = tF[i][2], a3_ = tF[i][3];
            tF[i][0] = a0_ * R[0][0] + a1_ * R[1][0] + a2_ * R[2][0];
            tF[i][1] = a0_ * R[0][1] + a1_ * R[1][1] + a2_ * R[2][1];
            tF[i][2] = a0_ * R[0][2] + a1_ * R[1][2] + a2_ * R[2][2];
            tF[i][3] = a0_ * ex + a1_ * ey + a2_ * ez + a3_;
        }
    }

    // 5th (final) Q build while mreg is hot; hand off to the fp64 kernel.
    build_q(mreg, tF, qf);

    float* to = outg + prob * 16;
    #pragma unroll
    for (int i = 0; i < 3; ++i)
        #pragma unroll
        for (int j = 0; j < 4; ++j)
            to[i * 4 + j] = tF[i][j];

    float* oo = outg + (long long)NPROB * 16 + prob * 36;
    #pragma unroll
    for (int i = 0; i < 28; ++i) oo[i] = qf[i];
}

// ============================ KERNEL 2: fp64 tail ============================
// Loads the 40 handoff scalars, runs the (proven, round-5/6) fp64 final step,
// overwrites both output slots with the real results. Own register allocation;
// VGPR count here is harmless (kernel is ~10 us, grid-capped at 2 waves/SIMD
// either way). No LDS, no barriers, no M access.
__global__ __launch_bounds__(256, 1) void gn_f64_tail_kernel(float* __restrict__ outg) {
    const long long prob = (long long)blockIdx.x * 256 + threadIdx.x;

    float* to = outg + prob * 16;
    float* oo = outg + (long long)NPROB * 16 + prob * 36;

    float tF[3][4];
    #pragma unroll
    for (int i = 0; i < 3; ++i)
        #pragma unroll
        for (int j = 0; j < 4; ++j)
            tF[i][j] = to[i * 4 + j];

    double q[28];
    #pragma unroll
    for (int i = 0; i < 28; ++i) q[i] = (double)oo[i];

    // regularization (fp64)
    const double trQ  = q[QI(3, 3)] + q[QI(4, 4)] + q[QI(5, 5)];
    const double regT = 1e-8 * fmax(trQ, 1.0);
    q[QI(0, 0)] += 10.0;
    q[QI(1, 1)] += 10.0;
    q[QI(2, 2)] += 10.0;
    q[QI(3, 3)] += regT;
    q[QI(4, 4)] += regT;
    q[QI(5, 5)] += regT;

    // reg2 = 1e-5 * (1 + max(Omega)), fmax tree
    const double a0 = fmax(q[QI(0,0)], q[QI(0,1)]);
    const double a1 = fmax(q[QI(0,2)], q[QI(0,3)]);
    const double a2 = fmax(q[QI(0,4)], q[QI(0,5)]);
    const double a3 = fmax(q[QI(1,1)], q[QI(1,2)]);
    const double a4 = fmax(q[QI(1,3)], q[QI(1,4)]);
    const double a5 = fmax(q[QI(1,5)], q[QI(2,2)]);
    const double a6 = fmax(q[QI(2,3)], q[QI(2,4)]);
    const double a7 = fmax(q[QI(2,5)], q[QI(3,3)]);
    const double a8 = fmax(q[QI(3,4)], q[QI(3,5)]);
    const double a9 = fmax(q[QI(4,4)], q[QI(4,5)]);
    const double b0 = fmax(a0, a1);
    const double b1 = fmax(a2, a3);
    const double b2 = fmax(a4, a5);
    const double b3 = fmax(a6, a7);
    const double b4 = fmax(fmax(a8, a9), q[QI(5,5)]);
    const double mx = fmax(fmax(b0, b1), fmax(fmax(b2, b3), b4));
    const double reg2 = 1e-5 * (1.0 + mx);

    // Omega (post-diag, pre-reg2) kept in registers for the epilogue.
    double om[21];
    #pragma unroll
    for (int k = 0; k < 6; ++k)
        #pragma unroll
        for (int l = k; l < 6; ++l)
            om[OI6(k, l)] = q[QI(k, l)];

    #pragma unroll
    for (int k = 0; k < 6; ++k) q[QI(k, k)] += reg2;

    // in-place symmetric GE on q (fp64), col 6 as RHS
    #pragma unroll
    for (int k = 0; k < 6; ++k) {
        const double inv = fast_rcp(q[QI(k, k)]);
        q[QI(k, k)] = inv;
        #pragma unroll
        for (int i = k + 1; i < 6; ++i) {
            const double f = q[QI(k, i)] * inv;
            #pragma unroll
            for (int j = i; j < 7; ++j) q[QI(i, j)] -= f * q[QI(k, j)];
        }
    }
    double x[6];
    #pragma unroll
    for (int i = 5; i >= 0; --i) {
        double s = q[QI(i, 6)];
        #pragma unroll
        for (int j = i + 1; j < 6; ++j) s -= q[QI(i, j)] * x[j];
        x[i] = s * q[QI(i, i)];
    }
    const double wx = -x[0], wy = -x[1], wz = -x[2];
    const double ux = -x[3], uy = -x[4], uz = -x[5];

    // fp64 closed-form expm of se(3): E = [[R, V*u],[0,1]]
    const double tsq = wx * wx + wy * wy + wz * wz;
    double A, B, Cc;
    if (tsq < 0.25) {
        A  = 1.0 + tsq * (-1.0/6 + tsq * (1.0/120 + tsq * (-1.0/5040 + tsq * (1.0/362880
             + tsq * (-1.0/39916800.0 + tsq * (1.0/6227020800.0 + tsq * (-1.0/1307674368000.0)))))));
        B  = 0.5 + tsq * (-1.0/24 + tsq * (1.0/720 + tsq * (-1.0/40320 + tsq * (1.0/3628800
             + tsq * (-1.0/479001600.0 + tsq * (1.0/87178291200.0 + tsq * (-1.0/20922789888000.0)))))));
        Cc = 1.0/6 + tsq * (-1.0/120 + tsq * (1.0/5040 + tsq * (-1.0/362880 + tsq * (1.0/39916800.0
             + tsq * (-1.0/6227020800.0 + tsq * (1.0/1307674368000.0 + tsq * (-1.0/355687428096000.0)))))));
    } else {
        const double th = sqrt(tsq);
        const double s = sin(th), c = cos(th);
        A  = s / th;
        B  = (1.0 - c) / tsq;
        Cc = (th - s) / (tsq * th);
    }
    const double K2xx = wx * wx - tsq, K2yy = wy * wy - tsq, K2zz = wz * wz - tsq;
    const double K2xy = wx * wy, K2xz = wx * wz, K2yz = wy * wz;
    double R[3][3];
    R[0][0] = 1.0 + B * K2xx;      R[0][1] = -A * wz + B * K2xy;  R[0][2] =  A * wy + B * K2xz;
    R[1][0] =  A * wz + B * K2xy;  R[1][1] = 1.0 + B * K2yy;      R[1][2] = -A * wx + B * K2yz;
    R[2][0] = -A * wy + B * K2xz;  R[2][1] =  A * wx + B * K2yz;  R[2][2] = 1.0 + B * K2zz;
    const double V00 = 1.0 + Cc * K2xx,      V01 = -B * wz + Cc * K2xy, V02 =  B * wy + Cc * K2xz;
    const double V10 =  B * wz + Cc * K2xy,  V11 = 1.0 + Cc * K2yy,     V12 = -B * wx + Cc * K2yz;
    const double V20 = -B * wy + Cc * K2xz,  V21 =  B * wx + Cc * K2yz, V22 = 1.0 + Cc * K2zz;
    const double ex = V00 * ux + V01 * uy + V02 * uz;
    const double ey = V10 * ux + V11 * uy + V12 * uz;
    const double ez = V20 * ux + V21 * uy + V22 * uz;

    // t = (double)tF, then T = T @ E
    double t[3][4];
    #pragma unroll
    for (int i = 0; i < 3; ++i) {
        const double a0_ = (double)tF[i][0], a1_ = (double)tF[i][1];
        const double a2_ = (double)tF[i][2], a3_ = (double)tF[i][3];
        t[i][0] = a0_ * R[0][0] + a1_ * R[1][0] + a2_ * R[2][0];
        t[i][1] = a0_ * R[0][1] + a1_ * R[1][1] + a2_ * R[2][1];
        t[i][2] = a0_ * R[0][2] + a1_ * R[1][2] + a2_ * R[2][2];
        t[i][3] = a0_ * ex + a1_ * ey + a2_ * ez + a3_;
    }

    // ---- outputs: overwrite both slots with the real results ----
    #pragma unroll
    for (int i = 0; i < 3; ++i)
        #pragma unroll
        for (int j = 0; j < 4; ++j)
            to[i * 4 + j] = (float)t[i][j];
    to[12] = 0.0f; to[13] = 0.0f; to[14] = 0.0f; to[15] = 1.0f;

    const double invden = 1.0 / (t[2][3] * t[2][3] + 1e-8);
    #pragma unroll
    for (int k = 0; k < 6; ++k)
        #pragma unroll
        for (int l = 0; l < 6; ++l)
            oo[k * 6 + l] = (float)(om[(k <= l) ? OI6(k, l) : OI6(l, k)] * invden);
}

extern "C" void kernel_launch(void* const* d_in, const int* in_sizes, int n_in,
                              void* d_out, int out_size, void* d_ws, size_t ws_size,
                              hipStream_t stream) {
    const float* Mg = (const float*)d_in[0];  // [64,2048,13,13] fp32
    const float* Tg = (const float*)d_in[1];  // [64,2048,4,4]  fp32
    float* out = (float*)d_out;               // [NPROB*16 + NPROB*36] fp32
    (void)in_sizes; (void)n_in; (void)out_size; (void)d_ws; (void)ws_size;

    const int threads = 256;
    const int blocks = NPROB / threads;  // 512
    gn_f32_kernel<<<blocks, threads, 0, stream>>>(Mg, Tg, out);
    gn_f64_tail_kernel<<<blocks, threads, 0, stream>>>(out);
}

// Round 8
// 200.426 us; speedup vs baseline: 1.0685x; 1.0685x over previous
//
#include <hip/hip_runtime.h>
#include <math.h>

#define NPROB (64 * 2048)

__host__ __device__ constexpr int TRI(int i, int j) { return i * 13 - i * (i - 1) / 2 + (j - i); }
__host__ __device__ constexpr int OI6(int i, int j) { return i * 6 - i * (i - 1) / 2 + (j - i); }
__host__ __device__ constexpr int QI(int i, int j)  { return i * 7 - i * (i - 1) / 2 + (j - i); }

// Sparse pattern of P's columns. Entry value = s * T[a][b], or s*1.0 if a==3.
// P rows (13): rot_rows(i) -> rows 3i..3i+2, ones row 9, translation rows 10..12.
struct PE { int r, a, b, s; };
__device__ constexpr int PLEN[7] = {6, 6, 6, 3, 3, 3, 13};
__device__ constexpr PE PAT[7][13] = {
    {{1,0,2,1},{2,0,1,-1},{4,1,2,1},{5,1,1,-1},{7,2,2,1},{8,2,1,-1}},
    {{0,0,2,-1},{2,0,0,1},{3,1,2,-1},{5,1,0,1},{6,2,2,-1},{8,2,0,1}},
    {{0,0,1,1},{1,0,0,-1},{3,1,1,1},{4,1,0,-1},{6,2,1,1},{7,2,0,-1}},
    {{10,0,0,1},{11,1,0,1},{12,2,0,1}},
    {{10,0,1,1},{11,1,1,1},{12,2,1,1}},
    {{10,0,2,1},{11,1,2,1},{12,2,2,1}},
    {{0,0,0,1},{1,0,1,1},{2,0,2,1},{3,1,0,1},{4,1,1,1},{5,1,2,1},
     {6,2,0,1},{7,2,1,1},{8,2,2,1},{9,3,0,1},{10,0,3,1},{11,1,3,1},{12,2,3,1}},
};

// Fast fp32 reciprocal: v_rcp_f32 + 1 Newton step.
__device__ __forceinline__ float fast_rcpf(float w) {
    float r = __builtin_amdgcn_rcpf(w);
    r = r * fmaf(-w, r, 2.0f);
    return r;
}

// fp32 Q = P^T M P build. SINGLE callsite in the kernel (code-shape rule:
// every fast build this session -- R1/R3/R4, 124 VGPR -- had one build region
// inside a uniform loop; every split-shape build -- R5/R6/R7 -- regalloc'd to
// 224+ VGPR and ran 1.5x slower, independent of fp32/fp64 content).
__device__ __forceinline__ void build_q(const float mreg[91], const float tf[3][4],
                                        float qf[28]) {
    #pragma unroll
    for (int l = 0; l < 7; ++l) {
        float y[13];
        #pragma unroll
        for (int r = 0; r < 13; ++r) y[r] = 0.0f;
        #pragma unroll
        for (int e = 0; e < 13; ++e) {
            if (e < PLEN[l]) {
                const PE pe = PAT[l][e];
                const float tt = (pe.a == 3) ? 1.0f : tf[pe.a][pe.b];
                const float cf = (pe.s > 0) ? tt : -tt;
                const int c = pe.r;
                #pragma unroll
                for (int r = 0; r < 13; ++r)
                    y[r] += cf * mreg[(r <= c) ? TRI(r, c) : TRI(c, r)];
            }
        }
        #pragma unroll
        for (int k = 0; k <= l; ++k) {
            float acc = 0.0f;
            #pragma unroll
            for (int e = 0; e < 13; ++e) {
                if (e < PLEN[k]) {
                    const PE pe = PAT[k][e];
                    const float tt = (pe.a == 3) ? 1.0f : tf[pe.a][pe.b];
                    const float cf = (pe.s > 0) ? tt : -tt;
                    acc += cf * y[pe.r];
                }
            }
            qf[QI(k, l)] = acc;
        }
    }
}

// All-fp32, single uniform loop. Numerics ledger: fp32 build (R3+) and fp32
// iterations 0-3 (R5+) are proven absmax-neutral (pinned at the fp32 output
// quantization floor 2^22). New this round: the FINAL solve/expm/update and
// invden also fp32 -> T gains ~ulp error (O(1) entries), Omega gains ~2e-7
// rel via invden. __sinf/__cosf: the big-angle branch only runs in early
// iterations (annihilated); final iteration has tiny v -> Taylor branch.
__global__ __launch_bounds__(256, 1) void gn5_kernel(const float* __restrict__ Mg,
                                                     const float* __restrict__ Tg,
                                                     float* __restrict__ outg) {
    const int tid  = threadIdx.x;
    const int lane = tid & 63;
    const int wv   = tid >> 6;
    const long long prob = (long long)blockIdx.x * 256 + tid;

    // Stage 64 problems (64*169 floats = 43.3 KB) at a time; each wave then
    // pulls its own symmetric triangle (91 fp32) into registers.
    __shared__ __align__(16) float buf[64 * 169];
    float mreg[91];

    #pragma unroll 1
    for (int w = 0; w < 4; ++w) {
        const long long c0 = (long long)blockIdx.x * 256 + (long long)w * 64;
        const float4* src = (const float4*)(Mg + c0 * 169);
        float4* dst = (float4*)buf;
        #pragma unroll 1
        for (int i = tid; i < (64 * 169) / 4; i += 256) dst[i] = src[i];
        __syncthreads();
        if (wv == w) {
            #pragma unroll
            for (int i = 0; i < 13; ++i)
                #pragma unroll
                for (int j = i; j < 13; ++j)
                    mreg[TRI(i, j)] = buf[lane * 169 + i * 13 + j];
        }
        __syncthreads();
    }

    // fp32 master pose (bottom row of input is (0,0,0,1) and stays so).
    float tF[3][4];
    {
        const float* tp = Tg + prob * 16;
        #pragma unroll
        for (int i = 0; i < 3; ++i)
            #pragma unroll
            for (int j = 0; j < 4; ++j)
                tF[i][j] = tp[i * 4 + j];
    }

    float qf[28];

    #pragma unroll 1
    for (int it = 0; it < 5; ++it) {
        build_q(mreg, tF, qf);

        // ---- regularization: diag(10,10,10,regT,regT,regT) ----
        const float trQ  = qf[QI(3, 3)] + qf[QI(4, 4)] + qf[QI(5, 5)];
        const float regT = 1e-8f * fmaxf(trQ, 1.0f);
        qf[QI(0, 0)] += 10.0f;
        qf[QI(1, 1)] += 10.0f;
        qf[QI(2, 2)] += 10.0f;
        qf[QI(3, 3)] += regT;
        qf[QI(4, 4)] += regT;
        qf[QI(5, 5)] += regT;

        // Last iteration: stash Omega (post-diag, pre-reg2) into the idle
        // staging buffer (thread-private slots, 256*21 fp32 = 21.5 KB <= 43.3 KB;
        // prologue finished with a barrier, slots are private -> no sync needed).
        // Wave-uniform branch; this is the ONLY asymmetry across iterations.
        if (it == 4) {
            #pragma unroll
            for (int k = 0; k < 6; ++k)
                #pragma unroll
                for (int l = k; l < 6; ++l)
                    buf[tid * 21 + OI6(k, l)] = qf[QI(k, l)];
        }

        // ---- reg2 = 1e-5 * (1 + max(Omega)) ----
        float mx = qf[QI(0, 0)];
        #pragma unroll
        for (int k = 0; k < 6; ++k)
            #pragma unroll
            for (int l = k; l < 6; ++l)
                mx = fmaxf(mx, qf[QI(k, l)]);
        const float reg2 = 1e-5f * (1.0f + mx);
        #pragma unroll
        for (int k = 0; k < 6; ++k) qf[QI(k, k)] += reg2;

        // ---- in-place symmetric GE on qf, col 6 as RHS ----
        #pragma unroll
        for (int k = 0; k < 6; ++k) {
            const float inv = fast_rcpf(qf[QI(k, k)]);
            qf[QI(k, k)] = inv;
            #pragma unroll
            for (int i = k + 1; i < 6; ++i) {
                const float f = qf[QI(k, i)] * inv;
                #pragma unroll
                for (int j = i; j < 7; ++j) qf[QI(i, j)] -= f * qf[QI(k, j)];
            }
        }
        float x[6];
        #pragma unroll
        for (int i = 5; i >= 0; --i) {
            float s = qf[QI(i, 6)];
            #pragma unroll
            for (int j = i + 1; j < 6; ++j) s -= qf[QI(i, j)] * x[j];
            x[i] = s * qf[QI(i, i)];
        }
        const float wx = -x[0], wy = -x[1], wz = -x[2];
        const float ux = -x[3], uy = -x[4], uz = -x[5];

        // ---- fp32 closed-form expm of se(3): E = [[R, V*u],[0,1]] ----
        const float tsq = wx * wx + wy * wy + wz * wz;
        float A, Bc, Cc;
        if (tsq < 0.25f) {
            A  = 1.0f + tsq * (-1.0f/6 + tsq * (1.0f/120 + tsq * (-1.0f/5040 + tsq * (1.0f/362880.0f))));
            Bc = 0.5f + tsq * (-1.0f/24 + tsq * (1.0f/720 + tsq * (-1.0f/40320 + tsq * (1.0f/3628800.0f))));
            Cc = 1.0f/6 + tsq * (-1.0f/120 + tsq * (1.0f/5040 + tsq * (-1.0f/362880 + tsq * (1.0f/39916800.0f))));
        } else {
            const float th = sqrtf(tsq);
            const float s = __sinf(th), c = __cosf(th);
            const float rth = fast_rcpf(th), rtsq = fast_rcpf(tsq);
            A  = s * rth;
            Bc = (1.0f - c) * rtsq;
            Cc = (th - s) * rtsq * rth;
        }
        const float K2xx = wx * wx - tsq, K2yy = wy * wy - tsq, K2zz = wz * wz - tsq;
        const float K2xy = wx * wy, K2xz = wx * wz, K2yz = wy * wz;
        float R[3][3];
        R[0][0] = 1.0f + Bc * K2xx;     R[0][1] = -A * wz + Bc * K2xy;  R[0][2] =  A * wy + Bc * K2xz;
        R[1][0] =  A * wz + Bc * K2xy;  R[1][1] = 1.0f + Bc * K2yy;     R[1][2] = -A * wx + Bc * K2yz;
        R[2][0] = -A * wy + Bc * K2xz;  R[2][1] =  A * wx + Bc * K2yz;  R[2][2] = 1.0f + Bc * K2zz;
        const float V00 = 1.0f + Cc * K2xx,     V01 = -Bc * wz + Cc * K2xy, V02 =  Bc * wy + Cc * K2xz;
        const float V10 =  Bc * wz + Cc * K2xy, V11 = 1.0f + Cc * K2yy,     V12 = -Bc * wx + Cc * K2yz;
        const float V20 = -Bc * wy + Cc * K2xz, V21 =  Bc * wx + Cc * K2yz, V22 = 1.0f + Cc * K2zz;
        const float ex = V00 * ux + V01 * uy + V02 * uz;
        const float ey = V10 * ux + V11 * uy + V12 * uz;
        const float ez = V20 * ux + V21 * uy + V22 * uz;

        // ---- T = T @ E ----
        #pragma unroll
        for (int i = 0; i < 3; ++i) {
            const float a0_ = tF[i][0], a1_ = tF[i][1], a2_ = tF[i][2], a3_ = tF[i][3];
            tF[i][0] = a0_ * R[0][0] + a1_ * R[1][0] + a2_ * R[2][0];
            tF[i][1] = a0_ * R[0][1] + a1_ * R[1][1] + a2_ * R[2][1];
            tF[i][2] = a0_ * R[0][2] + a1_ * R[1][2] + a2_ * R[2][2];
            tF[i][3] = a0_ * ex + a1_ * ey + a2_ * ez + a3_;
        }
    }

    // ---- outputs: T [NPROB,4,4] then Omega/(tz^2+1e-8) [NPROB,6,6], fp32 ----
    {
        float* to = outg + prob * 16;
        #pragma unroll
        for (int i = 0; i < 3; ++i)
            #pragma unroll
            for (int j = 0; j < 4; ++j)
                to[i * 4 + j] = tF[i][j];
        to[12] = 0.0f; to[13] = 0.0f; to[14] = 0.0f; to[15] = 1.0f;

        const float invden = 1.0f / (tF[2][3] * tF[2][3] + 1e-8f);
        float* oo = outg + (long long)NPROB * 16 + prob * 36;
        #pragma unroll
        for (int k = 0; k < 6; ++k)
            #pragma unroll
            for (int l = 0; l < 6; ++l)
                oo[k * 6 + l] = buf[tid * 21 + ((k <= l) ? OI6(k, l) : OI6(l, k))] * invden;
    }
}

extern "C" void kernel_launch(void* const* d_in, const int* in_sizes, int n_in,
                              void* d_out, int out_size, void* d_ws, size_t ws_size,
                              hipStream_t stream) {
    const float* Mg = (const float*)d_in[0];  // [64,2048,13,13] fp32
    const float* Tg = (const float*)d_in[1];  // [64,2048,4,4]  fp32
    float* out = (float*)d_out;               // [NPROB*16 + NPROB*36] fp32
    (void)in_sizes; (void)n_in; (void)out_size; (void)d_ws; (void)ws_size;

    const int threads = 256;
    const int blocks = NPROB / threads;  // 512
    gn5_kernel<<<blocks, threads, 0, stream>>>(Mg, Tg, out);
}

// Round 9
// 164.450 us; speedup vs baseline: 1.3023x; 1.2188x over previous
//
#include <hip/hip_runtime.h>
#include <math.h>

#define NPROB (64 * 2048)

__host__ __device__ constexpr int TRI(int i, int j) { return i * 13 - i * (i - 1) / 2 + (j - i); }
__host__ __device__ constexpr int OI6(int i, int j) { return i * 6 - i * (i - 1) / 2 + (j - i); }
__host__ __device__ constexpr int QI(int i, int j)  { return i * 7 - i * (i - 1) / 2 + (j - i); }

// Sparse pattern of P's columns. Entry value = s * T[a][b], or s*1.0 if a==3.
// P rows (13): rot_rows(i) -> rows 3i..3i+2, ones row 9, translation rows 10..12.
struct PE { int r, a, b, s; };
__device__ constexpr int PLEN[7] = {6, 6, 6, 3, 3, 3, 13};
__device__ constexpr PE PAT[7][13] = {
    {{1,0,2,1},{2,0,1,-1},{4,1,2,1},{5,1,1,-1},{7,2,2,1},{8,2,1,-1}},
    {{0,0,2,-1},{2,0,0,1},{3,1,2,-1},{5,1,0,1},{6,2,2,-1},{8,2,0,1}},
    {{0,0,1,1},{1,0,0,-1},{3,1,1,1},{4,1,0,-1},{6,2,1,1},{7,2,0,-1}},
    {{10,0,0,1},{11,1,0,1},{12,2,0,1}},
    {{10,0,1,1},{11,1,1,1},{12,2,1,1}},
    {{10,0,2,1},{11,1,2,1},{12,2,2,1}},
    {{0,0,0,1},{1,0,1,1},{2,0,2,1},{3,1,0,1},{4,1,1,1},{5,1,2,1},
     {6,2,0,1},{7,2,1,1},{8,2,2,1},{9,3,0,1},{10,0,3,1},{11,1,3,1},{12,2,3,1}},
};

// Fast fp64 reciprocal: v_rcp_f64 seed + 2 Newton steps -> ~1 ulp.
// Pivots are SPD-diagonal + reg, so w > 0 always.
__device__ __forceinline__ double fast_rcp(double w) {
    double r = __builtin_amdgcn_rcp(w);
    double e = fma(-w, r, 1.0);
    r = fma(r, e, r);
    e = fma(-w, r, 1.0);
    r = fma(r, e, r);
    return r;
}

// Fast fp32 reciprocal: v_rcp_f32 + 1 Newton step.
__device__ __forceinline__ float fast_rcpf(float w) {
    float r = __builtin_amdgcn_rcpf(w);
    r = r * fmaf(-w, r, 2.0f);
    return r;
}

// SESSION LEDGER (8 rounds): fp32 Q-build + fp64 tail (this shape) = 124 VGPR,
// 63-72 us. ANY fp32 scalar tail (R5/R7/R8) = 196-228 VGPR, 98-110 us, MORE
// emitted instructions than the fp64 tail -- SLP packs scalar fp32 into
// v_pk pairs (fp64 has no packed form, hence immune), paying register-pair
// alignment + shuffles. Keep the tail fp64. Only change vs the 62.7 us build:
// the big-angle trig is an 8-op fp32 island (ocml fp64 sin/cos blob removed;
// fp32 trig there proven absmax-neutral by R8).
__global__ __launch_bounds__(256, 1) void gn5_kernel(const float* __restrict__ Mg,
                                                     const float* __restrict__ Tg,
                                                     float* __restrict__ outg) {
    const int tid  = threadIdx.x;
    const int lane = tid & 63;
    const int wv   = tid >> 6;
    const long long prob = (long long)blockIdx.x * 256 + tid;

    // Stage 64 problems (64*169 floats = 43.3 KB) at a time; each wave then
    // pulls its own symmetric triangle (91 fp32) into registers.
    __shared__ __align__(16) float buf[64 * 169];
    float mreg[91];

    #pragma unroll 1
    for (int w = 0; w < 4; ++w) {
        const long long c0 = (long long)blockIdx.x * 256 + (long long)w * 64;
        const float4* src = (const float4*)(Mg + c0 * 169);
        float4* dst = (float4*)buf;
        #pragma unroll 1
        for (int i = tid; i < (64 * 169) / 4; i += 256) dst[i] = src[i];
        __syncthreads();
        if (wv == w) {
            #pragma unroll
            for (int i = 0; i < 13; ++i)
                #pragma unroll
                for (int j = i; j < 13; ++j)
                    mreg[TRI(i, j)] = buf[lane * 169 + i * 13 + j];
        }
        __syncthreads();
    }

    // Load T rows 0..2 (bottom row of input is (0,0,0,1) and stays so).
    double t[3][4];
    {
        const float* tp = Tg + prob * 16;
        #pragma unroll
        for (int i = 0; i < 3; ++i)
            #pragma unroll
            for (int j = 0; j < 4; ++j)
                t[i][j] = (double)tp[i * 4 + j];
    }

    double q[28];  // symmetric 7x7 upper triangle (fp64, post-conversion)

    #pragma unroll 1
    for (int it = 0; it < 5; ++it) {
        // fp32 copy of the pose: both stages of the Q build run in fp32.
        float tf[3][4];
        #pragma unroll
        for (int i = 0; i < 3; ++i)
            #pragma unroll
            for (int j = 0; j < 4; ++j)
                tf[i][j] = (float)t[i][j];

        // ---- Q = P^T M P via sparse columns, all-fp32 build ----
        float qf[28];
        #pragma unroll
        for (int l = 0; l < 7; ++l) {
            float y[13];
            #pragma unroll
            for (int r = 0; r < 13; ++r) y[r] = 0.0f;
            #pragma unroll
            for (int e = 0; e < 13; ++e) {
                if (e < PLEN[l]) {
                    const PE pe = PAT[l][e];
                    const float tt = (pe.a == 3) ? 1.0f : tf[pe.a][pe.b];
                    const float cf = (pe.s > 0) ? tt : -tt;
                    const int c = pe.r;
                    #pragma unroll
                    for (int r = 0; r < 13; ++r)
                        y[r] += cf * mreg[(r <= c) ? TRI(r, c) : TRI(c, r)];
                }
            }
            #pragma unroll
            for (int k = 0; k <= l; ++k) {
                float acc = 0.0f;
                #pragma unroll
                for (int e = 0; e < 13; ++e) {
                    if (e < PLEN[k]) {
                        const PE pe = PAT[k][e];
                        const float tt = (pe.a == 3) ? 1.0f : tf[pe.a][pe.b];
                        const float cf = (pe.s > 0) ? tt : -tt;
                        acc += cf * y[pe.r];
                    }
                }
                qf[QI(k, l)] = acc;
            }
        }
        #pragma unroll
        for (int i = 0; i < 28; ++i) q[i] = (double)qf[i];

        // ---- regularization: Omega = Q[0:6,0:6] + diag(10,10,10,regT,regT,regT) ----
        const double trQ  = q[QI(3, 3)] + q[QI(4, 4)] + q[QI(5, 5)];
        const double regT = 1e-8 * fmax(trQ, 1.0);
        q[QI(0, 0)] += 10.0;
        q[QI(1, 1)] += 10.0;
        q[QI(2, 2)] += 10.0;
        q[QI(3, 3)] += regT;
        q[QI(4, 4)] += regT;
        q[QI(5, 5)] += regT;

        // ---- _inv's extra reg: 1e-5 * (1 + max(Omega)), fmax tree ----
        const double a0 = fmax(q[QI(0,0)], q[QI(0,1)]);
        const double a1 = fmax(q[QI(0,2)], q[QI(0,3)]);
        const double a2 = fmax(q[QI(0,4)], q[QI(0,5)]);
        const double a3 = fmax(q[QI(1,1)], q[QI(1,2)]);
        const double a4 = fmax(q[QI(1,3)], q[QI(1,4)]);
        const double a5 = fmax(q[QI(1,5)], q[QI(2,2)]);
        const double a6 = fmax(q[QI(2,3)], q[QI(2,4)]);
        const double a7 = fmax(q[QI(2,5)], q[QI(3,3)]);
        const double a8 = fmax(q[QI(3,4)], q[QI(3,5)]);
        const double a9 = fmax(q[QI(4,4)], q[QI(4,5)]);
        const double b0 = fmax(a0, a1);
        const double b1 = fmax(a2, a3);
        const double b2 = fmax(a4, a5);
        const double b3 = fmax(a6, a7);
        const double b4 = fmax(fmax(a8, a9), q[QI(5,5)]);
        const double mx = fmax(fmax(b0, b1), fmax(fmax(b2, b3), b4));
        const double reg2 = 1e-5 * (1.0 + mx);

        // Last iteration: stash Omega (pre-reg2) in the idle staging buffer
        // before the in-place GE destroys q. Thread-private slots
        // (256 threads * 21 doubles = 43008 B <= 43264 B), no barrier needed.
        if (it == 4) {
            double* st = (double*)buf;
            #pragma unroll
            for (int k = 0; k < 6; ++k)
                #pragma unroll
                for (int l = k; l < 6; ++l)
                    st[(long long)tid * 21 + OI6(k, l)] = q[QI(k, l)];
        }

        #pragma unroll
        for (int k = 0; k < 6; ++k) q[QI(k, k)] += reg2;

        // ---- solve (Omega + reg2*I) x = g, v = -x: in-place symmetric GE on q,
        // col 6 carried as the RHS; pivot reciprocals overwrite the diagonal.
        #pragma unroll
        for (int k = 0; k < 6; ++k) {
            const double inv = fast_rcp(q[QI(k, k)]);
            q[QI(k, k)] = inv;
            #pragma unroll
            for (int i = k + 1; i < 6; ++i) {
                const double f = q[QI(k, i)] * inv;
                #pragma unroll
                for (int j = i; j < 7; ++j) q[QI(i, j)] -= f * q[QI(k, j)];
            }
        }
        double x[6];
        #pragma unroll
        for (int i = 5; i >= 0; --i) {
            double s = q[QI(i, 6)];
            #pragma unroll
            for (int j = i + 1; j < 6; ++j) s -= q[QI(i, j)] * x[j];
            x[i] = s * q[QI(i, i)];
        }
        const double wx = -x[0], wy = -x[1], wz = -x[2];
        const double ux = -x[3], uy = -x[4], uz = -x[5];

        // ---- closed-form expm of se(3): E = [[R, V*u],[0,1]] ----
        const double tsq = wx * wx + wy * wy + wz * wz;
        double A, B, Cc;
        if (tsq < 0.25) {
            // Taylor in t = theta^2, fp64-exact for t < 0.25
            A  = 1.0 + tsq * (-1.0/6 + tsq * (1.0/120 + tsq * (-1.0/5040 + tsq * (1.0/362880
                 + tsq * (-1.0/39916800.0 + tsq * (1.0/6227020800.0 + tsq * (-1.0/1307674368000.0)))))));
            B  = 0.5 + tsq * (-1.0/24 + tsq * (1.0/720 + tsq * (-1.0/40320 + tsq * (1.0/3628800
                 + tsq * (-1.0/479001600.0 + tsq * (1.0/87178291200.0 + tsq * (-1.0/20922789888000.0)))))));
            Cc = 1.0/6 + tsq * (-1.0/120 + tsq * (1.0/5040 + tsq * (-1.0/362880 + tsq * (1.0/39916800.0
                 + tsq * (-1.0/6227020800.0 + tsq * (1.0/1307674368000.0 + tsq * (-1.0/355687428096000.0)))))));
        } else {
            // fp32 island (8 ops): removes the inlined ocml fp64 sin/cos blob
            // whose register footprint is paid even when this branch never
            // executes. Branch only runs in early iterations (final-iteration
            // steps are tiny -> Taylor); fp32 trig here is absmax-neutral
            // (R8 ran ALL iterations' trig in fp32, absmax pinned at 2^22).
            const float tsqf = (float)tsq;
            const float thf  = sqrtf(tsqf);
            const float sf   = __sinf(thf), cf = __cosf(thf);
            const float rth  = fast_rcpf(thf), rtsq = fast_rcpf(tsqf);
            A  = (double)(sf * rth);
            B  = (double)((1.0f - cf) * rtsq);
            Cc = (double)((thf - sf) * rtsq * rth);
        }
        // K^2 = w w^T - tsq*I
        const double K2xx = wx * wx - tsq, K2yy = wy * wy - tsq, K2zz = wz * wz - tsq;
        const double K2xy = wx * wy, K2xz = wx * wz, K2yz = wy * wz;
        double R[3][3];
        R[0][0] = 1.0 + B * K2xx;      R[0][1] = -A * wz + B * K2xy;  R[0][2] =  A * wy + B * K2xz;
        R[1][0] =  A * wz + B * K2xy;  R[1][1] = 1.0 + B * K2yy;      R[1][2] = -A * wx + B * K2yz;
        R[2][0] = -A * wy + B * K2xz;  R[2][1] =  A * wx + B * K2yz;  R[2][2] = 1.0 + B * K2zz;
        const double V00 = 1.0 + Cc * K2xx,      V01 = -B * wz + Cc * K2xy, V02 =  B * wy + Cc * K2xz;
        const double V10 =  B * wz + Cc * K2xy,  V11 = 1.0 + Cc * K2yy,     V12 = -B * wx + Cc * K2yz;
        const double V20 = -B * wy + Cc * K2xz,  V21 =  B * wx + Cc * K2yz, V22 = 1.0 + Cc * K2zz;
        const double ex = V00 * ux + V01 * uy + V02 * uz;
        const double ey = V10 * ux + V11 * uy + V12 * uz;
        const double ez = V20 * ux + V21 * uy + V22 * uz;

        // ---- T = T @ E ----
        #pragma unroll
        for (int i = 0; i < 3; ++i) {
            const double a0_ = t[i][0], a1_ = t[i][1], a2_ = t[i][2], a3_ = t[i][3];
            t[i][0] = a0_ * R[0][0] + a1_ * R[1][0] + a2_ * R[2][0];
            t[i][1] = a0_ * R[0][1] + a1_ * R[1][1] + a2_ * R[2][1];
            t[i][2] = a0_ * R[0][2] + a1_ * R[1][2] + a2_ * R[2][2];
            t[i][3] = a0_ * ex + a1_ * ey + a2_ * ez + a3_;
        }
    }

    // ---- outputs: T [NPROB,4,4] then Omega/(tz^2+1e-8) [NPROB,6,6], fp32 ----
    {
        float* to = outg + prob * 16;
        #pragma unroll
        for (int i = 0; i < 3; ++i)
            #pragma unroll
            for (int j = 0; j < 4; ++j)
                to[i * 4 + j] = (float)t[i][j];
        to[12] = 0.0f; to[13] = 0.0f; to[14] = 0.0f; to[15] = 1.0f;

        const double invden = 1.0 / (t[2][3] * t[2][3] + 1e-8);
        const double* st = (const double*)buf;
        float* oo = outg + (long long)NPROB * 16 + prob * 36;
        #pragma unroll
        for (int k = 0; k < 6; ++k)
            #pragma unroll
            for (int l = 0; l < 6; ++l)
                oo[k * 6 + l] = (float)(st[(long long)tid * 21 + ((k <= l) ? OI6(k, l) : OI6(l, k))] * invden);
    }
}

extern "C" void kernel_launch(void* const* d_in, const int* in_sizes, int n_in,
                              void* d_out, int out_size, void* d_ws, size_t ws_size,
                              hipStream_t stream) {
    const float* Mg = (const float*)d_in[0];  // [64,2048,13,13] fp32
    const float* Tg = (const float*)d_in[1];  // [64,2048,4,4]  fp32
    float* out = (float*)d_out;               // [NPROB*16 + NPROB*36] fp32
    (void)in_sizes; (void)n_in; (void)out_size; (void)d_ws; (void)ws_size;

    const int threads = 256;
    const int blocks = NPROB / threads;  // 512
    gn5_kernel<<<blocks, threads, 0, stream>>>(Mg, Tg, out);
}

// Round 10
// 153.228 us; speedup vs baseline: 1.3976x; 1.0732x over previous
//
#include <hip/hip_runtime.h>
#include <math.h>

#define NPROB (64 * 2048)

__host__ __device__ constexpr int TRI(int i, int j) { return i * 13 - i * (i - 1) / 2 + (j - i); }
__host__ __device__ constexpr int OI6(int i, int j) { return i * 6 - i * (i - 1) / 2 + (j - i); }
__host__ __device__ constexpr int QI(int i, int j)  { return i * 7 - i * (i - 1) / 2 + (j - i); }

// Sparse pattern of P's columns. Entry value = s * T[a][b], or s*1.0 if a==3.
// P rows (13): rot_rows(i) -> rows 3i..3i+2, ones row 9, translation rows 10..12.
struct PE { int r, a, b, s; };
__device__ constexpr int PLEN[7] = {6, 6, 6, 3, 3, 3, 13};
__device__ constexpr PE PAT[7][13] = {
    {{1,0,2,1},{2,0,1,-1},{4,1,2,1},{5,1,1,-1},{7,2,2,1},{8,2,1,-1}},
    {{0,0,2,-1},{2,0,0,1},{3,1,2,-1},{5,1,0,1},{6,2,2,-1},{8,2,0,1}},
    {{0,0,1,1},{1,0,0,-1},{3,1,1,1},{4,1,0,-1},{6,2,1,1},{7,2,0,-1}},
    {{10,0,0,1},{11,1,0,1},{12,2,0,1}},
    {{10,0,1,1},{11,1,1,1},{12,2,1,1}},
    {{10,0,2,1},{11,1,2,1},{12,2,2,1}},
    {{0,0,0,1},{1,0,1,1},{2,0,2,1},{3,1,0,1},{4,1,1,1},{5,1,2,1},
     {6,2,0,1},{7,2,1,1},{8,2,2,1},{9,3,0,1},{10,0,3,1},{11,1,3,1},{12,2,3,1}},
};

// Fast fp64 reciprocal: v_rcp_f64 seed + 2 Newton steps -> ~1 ulp.
// Pivots are SPD-diagonal + reg, so w > 0 always.
__device__ __forceinline__ double fast_rcp(double w) {
    double r = __builtin_amdgcn_rcp(w);
    double e = fma(-w, r, 1.0);
    r = fma(r, e, r);
    e = fma(-w, r, 1.0);
    r = fma(r, e, r);
    return r;
}

// Fast fp32 reciprocal: v_rcp_f32 + 1 Newton step.
__device__ __forceinline__ float fast_rcpf(float w) {
    float r = __builtin_amdgcn_rcpf(w);
    r = r * fmaf(-w, r, 2.0f);
    return r;
}

// SESSION LEDGER: fp32 Q-build + fp64 tail = 120-124 VGPR, 63-72 us across 4
// instruction-mix variants (latency-bound, issue-count-insensitive). Any fp32
// scalar tail = 196-228 VGPR + scratch, 98-110 us (compiler pathology, R5/7/8).
// Wave-split parallelism loses 2x to barrier convoys (R2). This round isolates
// the LAST untested serial term: the staged prologue (8 block-wide barriers +
// LDS round-trip + 3/4-idle extraction). Replaced with direct global->register
// triangle loads (row runs merge to dwordx4/x2; every fetched byte is still
// consumed, so HBM traffic is unchanged). Kernel is now BARRIER-FREE.
__global__ __launch_bounds__(256, 1) void gn5_kernel(const float* __restrict__ Mg,
                                                     const float* __restrict__ Tg,
                                                     float* __restrict__ outg) {
    const int tid  = threadIdx.x;
    const long long prob = (long long)blockIdx.x * 256 + tid;

    // LDS: only the last-iteration Omega stash (thread-private slots).
    __shared__ __align__(16) double st[256 * 21];  // 43008 B

    // Direct triangle load: thread's M is contiguous [169] at prob*169.
    // Row i keeps its upper part [i..12] -> contiguous runs the compiler
    // merges into wide loads; ~31 load instrs, all issued before first use.
    float mreg[91];
    {
        const float* mp = Mg + prob * 169;
        #pragma unroll
        for (int i = 0; i < 13; ++i)
            #pragma unroll
            for (int j = i; j < 13; ++j)
                mreg[TRI(i, j)] = mp[i * 13 + j];
    }

    // Load T rows 0..2 (bottom row of input is (0,0,0,1) and stays so).
    double t[3][4];
    {
        const float* tp = Tg + prob * 16;
        #pragma unroll
        for (int i = 0; i < 3; ++i)
            #pragma unroll
            for (int j = 0; j < 4; ++j)
                t[i][j] = (double)tp[i * 4 + j];
    }

    double q[28];  // symmetric 7x7 upper triangle (fp64, post-conversion)

    #pragma unroll 1
    for (int it = 0; it < 5; ++it) {
        // fp32 copy of the pose: both stages of the Q build run in fp32.
        float tf[3][4];
        #pragma unroll
        for (int i = 0; i < 3; ++i)
            #pragma unroll
            for (int j = 0; j < 4; ++j)
                tf[i][j] = (float)t[i][j];

        // ---- Q = P^T M P via sparse columns, all-fp32 build ----
        float qf[28];
        #pragma unroll
        for (int l = 0; l < 7; ++l) {
            float y[13];
            #pragma unroll
            for (int r = 0; r < 13; ++r) y[r] = 0.0f;
            #pragma unroll
            for (int e = 0; e < 13; ++e) {
                if (e < PLEN[l]) {
                    const PE pe = PAT[l][e];
                    const float tt = (pe.a == 3) ? 1.0f : tf[pe.a][pe.b];
                    const float cf = (pe.s > 0) ? tt : -tt;
                    const int c = pe.r;
                    #pragma unroll
                    for (int r = 0; r < 13; ++r)
                        y[r] += cf * mreg[(r <= c) ? TRI(r, c) : TRI(c, r)];
                }
            }
            #pragma unroll
            for (int k = 0; k <= l; ++k) {
                float acc = 0.0f;
                #pragma unroll
                for (int e = 0; e < 13; ++e) {
                    if (e < PLEN[k]) {
                        const PE pe = PAT[k][e];
                        const float tt = (pe.a == 3) ? 1.0f : tf[pe.a][pe.b];
                        const float cf = (pe.s > 0) ? tt : -tt;
                        acc += cf * y[pe.r];
                    }
                }
                qf[QI(k, l)] = acc;
            }
        }
        #pragma unroll
        for (int i = 0; i < 28; ++i) q[i] = (double)qf[i];

        // ---- regularization: Omega = Q[0:6,0:6] + diag(10,10,10,regT,regT,regT) ----
        const double trQ  = q[QI(3, 3)] + q[QI(4, 4)] + q[QI(5, 5)];
        const double regT = 1e-8 * fmax(trQ, 1.0);
        q[QI(0, 0)] += 10.0;
        q[QI(1, 1)] += 10.0;
        q[QI(2, 2)] += 10.0;
        q[QI(3, 3)] += regT;
        q[QI(4, 4)] += regT;
        q[QI(5, 5)] += regT;

        // ---- _inv's extra reg: 1e-5 * (1 + max(Omega)), fmax tree ----
        const double a0 = fmax(q[QI(0,0)], q[QI(0,1)]);
        const double a1 = fmax(q[QI(0,2)], q[QI(0,3)]);
        const double a2 = fmax(q[QI(0,4)], q[QI(0,5)]);
        const double a3 = fmax(q[QI(1,1)], q[QI(1,2)]);
        const double a4 = fmax(q[QI(1,3)], q[QI(1,4)]);
        const double a5 = fmax(q[QI(1,5)], q[QI(2,2)]);
        const double a6 = fmax(q[QI(2,3)], q[QI(2,4)]);
        const double a7 = fmax(q[QI(2,5)], q[QI(3,3)]);
        const double a8 = fmax(q[QI(3,4)], q[QI(3,5)]);
        const double a9 = fmax(q[QI(4,4)], q[QI(4,5)]);
        const double b0 = fmax(a0, a1);
        const double b1 = fmax(a2, a3);
        const double b2 = fmax(a4, a5);
        const double b3 = fmax(a6, a7);
        const double b4 = fmax(fmax(a8, a9), q[QI(5,5)]);
        const double mx = fmax(fmax(b0, b1), fmax(fmax(b2, b3), b4));
        const double reg2 = 1e-5 * (1.0 + mx);

        // Last iteration: stash Omega (pre-reg2) before the in-place GE
        // destroys q. Thread-private slots, no synchronization needed.
        if (it == 4) {
            #pragma unroll
            for (int k = 0; k < 6; ++k)
                #pragma unroll
                for (int l = k; l < 6; ++l)
                    st[tid * 21 + OI6(k, l)] = q[QI(k, l)];
        }

        #pragma unroll
        for (int k = 0; k < 6; ++k) q[QI(k, k)] += reg2;

        // ---- solve (Omega + reg2*I) x = g, v = -x: in-place symmetric GE on q,
        // col 6 carried as the RHS; pivot reciprocals overwrite the diagonal.
        #pragma unroll
        for (int k = 0; k < 6; ++k) {
            const double inv = fast_rcp(q[QI(k, k)]);
            q[QI(k, k)] = inv;
            #pragma unroll
            for (int i = k + 1; i < 6; ++i) {
                const double f = q[QI(k, i)] * inv;
                #pragma unroll
                for (int j = i; j < 7; ++j) q[QI(i, j)] -= f * q[QI(k, j)];
            }
        }
        double x[6];
        #pragma unroll
        for (int i = 5; i >= 0; --i) {
            double s = q[QI(i, 6)];
            #pragma unroll
            for (int j = i + 1; j < 6; ++j) s -= q[QI(i, j)] * x[j];
            x[i] = s * q[QI(i, i)];
        }
        const double wx = -x[0], wy = -x[1], wz = -x[2];
        const double ux = -x[3], uy = -x[4], uz = -x[5];

        // ---- closed-form expm of se(3): E = [[R, V*u],[0,1]] ----
        const double tsq = wx * wx + wy * wy + wz * wz;
        double A, B, Cc;
        if (tsq < 0.25) {
            // Taylor in t = theta^2, fp64-exact for t < 0.25
            A  = 1.0 + tsq * (-1.0/6 + tsq * (1.0/120 + tsq * (-1.0/5040 + tsq * (1.0/362880
                 + tsq * (-1.0/39916800.0 + tsq * (1.0/6227020800.0 + tsq * (-1.0/1307674368000.0)))))));
            B  = 0.5 + tsq * (-1.0/24 + tsq * (1.0/720 + tsq * (-1.0/40320 + tsq * (1.0/3628800
                 + tsq * (-1.0/479001600.0 + tsq * (1.0/87178291200.0 + tsq * (-1.0/20922789888000.0)))))));
            Cc = 1.0/6 + tsq * (-1.0/120 + tsq * (1.0/5040 + tsq * (-1.0/362880 + tsq * (1.0/39916800.0
                 + tsq * (-1.0/6227020800.0 + tsq * (1.0/1307674368000.0 + tsq * (-1.0/355687428096000.0)))))));
        } else {
            // fp32 island (8 ops, R9-proven): avoids the inlined ocml fp64
            // sin/cos blob. Branch only runs in early iterations; fp32 trig
            // there is absmax-neutral (R8 evidence).
            const float tsqf = (float)tsq;
            const float thf  = sqrtf(tsqf);
            const float sf   = __sinf(thf), cf = __cosf(thf);
            const float rth  = fast_rcpf(thf), rtsq = fast_rcpf(tsqf);
            A  = (double)(sf * rth);
            B  = (double)((1.0f - cf) * rtsq);
            Cc = (double)((thf - sf) * rtsq * rth);
        }
        // K^2 = w w^T - tsq*I
        const double K2xx = wx * wx - tsq, K2yy = wy * wy - tsq, K2zz = wz * wz - tsq;
        const double K2xy = wx * wy, K2xz = wx * wz, K2yz = wy * wz;
        double R[3][3];
        R[0][0] = 1.0 + B * K2xx;      R[0][1] = -A * wz + B * K2xy;  R[0][2] =  A * wy + B * K2xz;
        R[1][0] =  A * wz + B * K2xy;  R[1][1] = 1.0 + B * K2yy;      R[1][2] = -A * wx + B * K2yz;
        R[2][0] = -A * wy + B * K2xz;  R[2][1] =  A * wx + B * K2yz;  R[2][2] = 1.0 + B * K2zz;
        const double V00 = 1.0 + Cc * K2xx,      V01 = -B * wz + Cc * K2xy, V02 =  B * wy + Cc * K2xz;
        const double V10 =  B * wz + Cc * K2xy,  V11 = 1.0 + Cc * K2yy,     V12 = -B * wx + Cc * K2yz;
        const double V20 = -B * wy + Cc * K2xz,  V21 =  B * wx + Cc * K2yz, V22 = 1.0 + Cc * K2zz;
        const double ex = V00 * ux + V01 * uy + V02 * uz;
        const double ey = V10 * ux + V11 * uy + V12 * uz;
        const double ez = V20 * ux + V21 * uy + V22 * uz;

        // ---- T = T @ E ----
        #pragma unroll
        for (int i = 0; i < 3; ++i) {
            const double a0_ = t[i][0], a1_ = t[i][1], a2_ = t[i][2], a3_ = t[i][3];
            t[i][0] = a0_ * R[0][0] + a1_ * R[1][0] + a2_ * R[2][0];
            t[i][1] = a0_ * R[0][1] + a1_ * R[1][1] + a2_ * R[2][1];
            t[i][2] = a0_ * R[0][2] + a1_ * R[1][2] + a2_ * R[2][2];
            t[i][3] = a0_ * ex + a1_ * ey + a2_ * ez + a3_;
        }
    }

    // ---- outputs: T [NPROB,4,4] then Omega/(tz^2+1e-8) [NPROB,6,6], fp32 ----
    {
        float* to = outg + prob * 16;
        #pragma unroll
        for (int i = 0; i < 3; ++i)
            #pragma unroll
            for (int j = 0; j < 4; ++j)
                to[i * 4 + j] = (float)t[i][j];
        to[12] = 0.0f; to[13] = 0.0f; to[14] = 0.0f; to[15] = 1.0f;

        const double invden = 1.0 / (t[2][3] * t[2][3] + 1e-8);
        float* oo = outg + (long long)NPROB * 16 + prob * 36;
        #pragma unroll
        for (int k = 0; k < 6; ++k)
            #pragma unroll
            for (int l = 0; l < 6; ++l)
                oo[k * 6 + l] = (float)(st[tid * 21 + ((k <= l) ? OI6(k, l) : OI6(l, k))] * invden);
    }
}

extern "C" void kernel_launch(void* const* d_in, const int* in_sizes, int n_in,
                              void* d_out, int out_size, void* d_ws, size_t ws_size,
                              hipStream_t stream) {
    const float* Mg = (const float*)d_in[0];  // [64,2048,13,13] fp32
    const float* Tg = (const float*)d_in[1];  // [64,2048,4,4]  fp32
    float* out = (float*)d_out;               // [NPROB*16 + NPROB*36] fp32
    (void)in_sizes; (void)n_in; (void)out_size; (void)d_ws; (void)ws_size;

    const int threads = 256;
    const int blocks = NPROB / threads;  // 512
    gn5_kernel<<<blocks, threads, 0, stream>>>(Mg, Tg, out);
}